// Round 1
// baseline (1170.424 us; speedup 1.0000x reference)
//
#include <hip/hip_runtime.h>

// Problem constants (from reference): N=500000 (taken from in_sizes), D=256, K=512, OUT=32
#define DFEAT 256
#define KINST 512
#define OUTC  32

// ---------- Phase 1: counts + coordinate sums (atomic, cheap) ----------
__global__ void count_coord_kernel(const int* __restrict__ ids,
                                   const float* __restrict__ coords,
                                   int* __restrict__ counts,
                                   float* __restrict__ csum,
                                   int n) {
    int i = blockIdx.x * blockDim.x + threadIdx.x;
    if (i >= n) return;
    int id = ids[i];
    if (id < 0) return;
    atomicAdd(&counts[id], 1);
    atomicAdd(&csum[id * 3 + 0], coords[i * 3 + 0]);
    atomicAdd(&csum[id * 3 + 1], coords[i * 3 + 1]);
    atomicAdd(&csum[id * 3 + 2], coords[i * 3 + 2]);
}

// ---------- Phase 2: exclusive scan of counts (one block, 512 threads) ----------
__global__ void scan_kernel(const int* __restrict__ counts, int* __restrict__ offsets) {
    __shared__ int s[KINST];
    int t = threadIdx.x;
    int c = counts[t];
    s[t] = c;
    __syncthreads();
    for (int off = 1; off < KINST; off <<= 1) {
        int add = (t >= off) ? s[t - off] : 0;
        __syncthreads();
        s[t] += add;
        __syncthreads();
    }
    offsets[t] = s[t] - c;   // exclusive prefix
}

// ---------- Phase 3: scatter point indices into buckets ----------
__global__ void scatter_kernel(const int* __restrict__ ids,
                               const int* __restrict__ offsets,
                               int* __restrict__ cursors,
                               int* __restrict__ bucket,
                               int n) {
    int i = blockIdx.x * blockDim.x + threadIdx.x;
    if (i >= n) return;
    int id = ids[i];
    if (id < 0) return;
    int pos = offsets[id] + atomicAdd(&cursors[id], 1);
    bucket[pos] = i;
}

// ---------- Phase 4: gather + mean. One block per instance. ----------
// 512 threads = 8 waves. Wave w ("sub") processes bucket entries with
// local index ≡ w or w+8 (mod 16) -> 16 rows in flight per block-iter.
// Each 64-lane wave reads one full row (64 x float4 = 1 KB, coalesced).
#define BUCKET_CHUNK 2048
__global__ __launch_bounds__(512) void gather_kernel(const float4* __restrict__ feat4,
                                                     const int* __restrict__ bucket,
                                                     const int* __restrict__ offsets,
                                                     const int* __restrict__ counts,
                                                     float* __restrict__ emb_out) {
    __shared__ int bl[BUCKET_CHUNK];
    __shared__ float red[512 * 4];

    int k   = blockIdx.x;
    int off = offsets[k];
    int cnt = counts[k];

    int sub = threadIdx.x >> 6;   // wave id, 0..7
    int f4  = threadIdx.x & 63;   // float4 column within the row

    float a0x = 0.f, a0y = 0.f, a0z = 0.f, a0w = 0.f;
    float a1x = 0.f, a1y = 0.f, a1z = 0.f, a1w = 0.f;

    for (int base = 0; base < cnt; base += BUCKET_CHUNK) {
        int chunk = cnt - base;
        if (chunk > BUCKET_CHUNK) chunk = BUCKET_CHUNK;
        // stage bucket indices into LDS (coalesced), removes per-iter pointer chase
        for (int t = threadIdx.x; t < chunk; t += 512) bl[t] = bucket[off + base + t];
        __syncthreads();

        int i = sub;
        for (; i + 8 < chunk; i += 16) {
            int r0 = bl[i];
            int r1 = bl[i + 8];
            float4 v0 = feat4[(long)r0 * 64 + f4];
            float4 v1 = feat4[(long)r1 * 64 + f4];
            a0x += v0.x; a0y += v0.y; a0z += v0.z; a0w += v0.w;
            a1x += v1.x; a1y += v1.y; a1z += v1.z; a1w += v1.w;
        }
        if (i < chunk) {
            int r = bl[i];
            float4 v = feat4[(long)r * 64 + f4];
            a0x += v.x; a0y += v.y; a0z += v.z; a0w += v.w;
        }
        __syncthreads();   // protect bl before next staging
    }

    a0x += a1x; a0y += a1y; a0z += a1z; a0w += a1w;

    red[threadIdx.x * 4 + 0] = a0x;
    red[threadIdx.x * 4 + 1] = a0y;
    red[threadIdx.x * 4 + 2] = a0z;
    red[threadIdx.x * 4 + 3] = a0w;
    __syncthreads();

    if (sub == 0) {
        float tx = 0.f, ty = 0.f, tz = 0.f, tw = 0.f;
        #pragma unroll
        for (int s = 0; s < 8; s++) {
            int b = (s * 64 + f4) * 4;
            tx += red[b + 0]; ty += red[b + 1]; tz += red[b + 2]; tw += red[b + 3];
        }
        float inv = 1.0f / (float)(cnt > 1 ? cnt : 1);
        float4 o;
        o.x = tx * inv; o.y = ty * inv; o.z = tz * inv; o.w = tw * inv;
        ((float4*)emb_out)[(long)k * 64 + f4] = o;
    }
}

// ---------- Phase 5: MLP + centroids. One block (64 threads) per instance. ----------
__global__ __launch_bounds__(64) void mlp_kernel(const float* __restrict__ emb,
                                                 const float* __restrict__ W1,
                                                 const float* __restrict__ W2,
                                                 const float* __restrict__ W3,
                                                 const float* __restrict__ b3,
                                                 const float* __restrict__ csum,
                                                 const int* __restrict__ counts,
                                                 float* __restrict__ cent_out,
                                                 float* __restrict__ mlp_out) {
    int k = blockIdx.x;
    int j = threadIdx.x;   // 0..63
    __shared__ float e[DFEAT];
    __shared__ float h1[64];
    __shared__ float h2[64];

    float4 ev = ((const float4*)emb)[(long)k * 64 + j];
    e[j * 4 + 0] = ev.x; e[j * 4 + 1] = ev.y; e[j * 4 + 2] = ev.z; e[j * 4 + 3] = ev.w;
    __syncthreads();

    float acc = 0.f;
    #pragma unroll 8
    for (int d = 0; d < DFEAT; d++) acc += e[d] * W1[d * 64 + j];
    h1[j] = fmaxf(acc, 0.f);
    __syncthreads();

    acc = 0.f;
    #pragma unroll 8
    for (int d = 0; d < 64; d++) acc += h1[d] * W2[d * 64 + j];
    h2[j] = fmaxf(acc, 0.f);
    __syncthreads();

    if (j < OUTC) {
        float o = b3[j];
        #pragma unroll 8
        for (int d = 0; d < 64; d++) o += h2[d] * W3[d * OUTC + j];
        mlp_out[k * OUTC + j] = o;
    }
    if (j < 3) {
        float denom = (float)(counts[k] > 1 ? counts[k] : 1);
        cent_out[k * 3 + j] = csum[k * 3 + j] / denom;
    }
}

extern "C" void kernel_launch(void* const* d_in, const int* in_sizes, int n_in,
                              void* d_out, int out_size, void* d_ws, size_t ws_size,
                              hipStream_t stream) {
    const float* features = (const float*)d_in[0];
    const float* coords   = (const float*)d_in[1];
    const int*   ids      = (const int*)d_in[2];
    // d_in[3] = num_instances (K=512, hardcoded)
    const float* W1 = (const float*)d_in[4];
    const float* W2 = (const float*)d_in[5];
    const float* W3 = (const float*)d_in[6];
    const float* b3 = (const float*)d_in[7];

    int n = in_sizes[2];   // number of points

    float* out      = (float*)d_out;
    float* emb_out  = out;                          // [512, 256]
    float* cent_out = out + (long)KINST * DFEAT;    // [512, 3]
    float* mlp_out  = cent_out + (long)KINST * 3;   // [512, 32]

    // workspace layout (ws poisoned 0xAA each call -> zero what we accumulate into)
    char* ws = (char*)d_ws;
    int*   counts  = (int*)(ws + 0);        // 512 * 4   = 2048
    int*   cursors = (int*)(ws + 2048);     // 512 * 4   = 2048
    float* csum    = (float*)(ws + 4096);   // 512*3*4   = 6144
    int*   offsets = (int*)(ws + 10240);    // 512 * 4   = 2048  (ends at 12288)
    int*   bucket  = (int*)(ws + 12288);    // n * 4

    hipMemsetAsync(d_ws, 0, 10240, stream);   // zero counts/cursors/csum

    int blocks = (n + 255) / 256;
    count_coord_kernel<<<blocks, 256, 0, stream>>>(ids, coords, counts, csum, n);
    scan_kernel<<<1, KINST, 0, stream>>>(counts, offsets);
    scatter_kernel<<<blocks, 256, 0, stream>>>(ids, offsets, cursors, bucket, n);
    gather_kernel<<<KINST, 512, 0, stream>>>((const float4*)features, bucket, offsets, counts, emb_out);
    mlp_kernel<<<KINST, 64, 0, stream>>>(emb_out, W1, W2, W3, b3, csum, counts, cent_out, mlp_out);
}

// Round 2
// 711.155 us; speedup vs baseline: 1.6458x; 1.6458x over previous
//
#include <hip/hip_runtime.h>

// Problem constants (from reference): N=500000 (from in_sizes), D=256, K=512, OUT=32
#define DFEAT 256
#define KINST 512
#define OUTC  32
#define CHUNK 4096          // points per block for hist/scatter kernels
#define BUCKET_CHUNK 2048   // bucket indices staged in LDS per gather iteration

// ---------- Phase 1: global histogram via LDS aggregation ----------
__global__ __launch_bounds__(256) void hist_kernel(const int* __restrict__ ids,
                                                   int* __restrict__ counts, int n) {
    __shared__ int hist[KINST];
    int start = blockIdx.x * CHUNK;
    int len = n - start;
    if (len > CHUNK) len = CHUNK;
    for (int b = threadIdx.x; b < KINST; b += 256) hist[b] = 0;
    __syncthreads();
    for (int l = threadIdx.x; l < len; l += 256) {
        int id = ids[start + l];
        if (id >= 0) atomicAdd(&hist[id], 1);      // LDS atomic
    }
    __syncthreads();
    for (int b = threadIdx.x; b < KINST; b += 256) {
        int c = hist[b];
        if (c) atomicAdd(&counts[b], c);           // one global atomic per (block,bin)
    }
}

// ---------- Phase 2: exclusive scan of counts (one block, 512 threads) ----------
__global__ void scan_kernel(const int* __restrict__ counts, int* __restrict__ offsets) {
    __shared__ int s[KINST];
    int t = threadIdx.x;
    int c = counts[t];
    s[t] = c;
    __syncthreads();
    for (int off = 1; off < KINST; off <<= 1) {
        int add = (t >= off) ? s[t - off] : 0;
        __syncthreads();
        s[t] += add;
        __syncthreads();
    }
    offsets[t] = s[t] - c;   // exclusive prefix
}

// ---------- Phase 3: scatter with block-level reservation ----------
__global__ __launch_bounds__(256) void scatter2_kernel(const int* __restrict__ ids,
                                                       const int* __restrict__ offsets,
                                                       int* __restrict__ cursor,
                                                       int* __restrict__ bucket, int n) {
    __shared__ int ids_s[CHUNK];
    __shared__ int hist[KINST];
    __shared__ int bases[KINST];
    __shared__ int lcur[KINST];
    int start = blockIdx.x * CHUNK;
    int len = n - start;
    if (len > CHUNK) len = CHUNK;
    for (int b = threadIdx.x; b < KINST; b += 256) { hist[b] = 0; lcur[b] = 0; }
    for (int l = threadIdx.x; l < len; l += 256) ids_s[l] = ids[start + l];
    __syncthreads();
    for (int l = threadIdx.x; l < len; l += 256) {
        int id = ids_s[l];
        if (id >= 0) atomicAdd(&hist[id], 1);      // LDS atomic
    }
    __syncthreads();
    for (int b = threadIdx.x; b < KINST; b += 256) {
        int c = hist[b];
        bases[b] = c ? (offsets[b] + atomicAdd(&cursor[b], c)) : 0;  // one global atomic per (block,bin)
    }
    __syncthreads();
    for (int l = threadIdx.x; l < len; l += 256) {
        int id = ids_s[l];
        if (id >= 0) {
            int w = atomicAdd(&lcur[id], 1);        // LDS atomic
            bucket[bases[id] + w] = start + l;
        }
    }
}

// ---------- Phase 4: gather + mean (features) + coord sums + centroids ----------
// One block per instance, 512 threads = 8 waves. Each wave reads whole 1 KB
// feature rows (64 x float4, coalesced); coords summed via the staged bucket.
__global__ __launch_bounds__(512) void gather_kernel(const float4* __restrict__ feat4,
                                                     const float* __restrict__ coords,
                                                     const int* __restrict__ bucket,
                                                     const int* __restrict__ offsets,
                                                     const int* __restrict__ counts,
                                                     float* __restrict__ emb_out,
                                                     float* __restrict__ cent_out) {
    __shared__ int bl[BUCKET_CHUNK];
    __shared__ float red[2048];

    int k   = blockIdx.x;
    int off = offsets[k];
    int cnt = counts[k];

    int sub = threadIdx.x >> 6;   // wave id, 0..7
    int f4  = threadIdx.x & 63;   // float4 column within the row

    float a0x = 0.f, a0y = 0.f, a0z = 0.f, a0w = 0.f;
    float a1x = 0.f, a1y = 0.f, a1z = 0.f, a1w = 0.f;
    float cx = 0.f, cy = 0.f, cz = 0.f;

    for (int base = 0; base < cnt; base += BUCKET_CHUNK) {
        int chunk = cnt - base;
        if (chunk > BUCKET_CHUNK) chunk = BUCKET_CHUNK;
        for (int t = threadIdx.x; t < chunk; t += 512) bl[t] = bucket[off + base + t];
        __syncthreads();

        // coords partial sums (small gathered reads, L2-friendly)
        for (int t = threadIdx.x; t < chunk; t += 512) {
            long r = bl[t];
            cx += coords[r * 3 + 0];
            cy += coords[r * 3 + 1];
            cz += coords[r * 3 + 2];
        }

        // feature rows, 16 in flight per block
        int i = sub;
        for (; i + 8 < chunk; i += 16) {
            int r0 = bl[i];
            int r1 = bl[i + 8];
            float4 v0 = feat4[(long)r0 * 64 + f4];
            float4 v1 = feat4[(long)r1 * 64 + f4];
            a0x += v0.x; a0y += v0.y; a0z += v0.z; a0w += v0.w;
            a1x += v1.x; a1y += v1.y; a1z += v1.z; a1w += v1.w;
        }
        if (i < chunk) {
            int r = bl[i];
            float4 v = feat4[(long)r * 64 + f4];
            a0x += v.x; a0y += v.y; a0z += v.z; a0w += v.w;
        }
        __syncthreads();   // protect bl before next staging
    }

    a0x += a1x; a0y += a1y; a0z += a1z; a0w += a1w;

    float inv = 1.0f / (float)(cnt > 1 ? cnt : 1);

    // feature reduction across the 8 waves
    red[threadIdx.x * 4 + 0] = a0x;
    red[threadIdx.x * 4 + 1] = a0y;
    red[threadIdx.x * 4 + 2] = a0z;
    red[threadIdx.x * 4 + 3] = a0w;
    __syncthreads();
    if (sub == 0) {
        float tx = 0.f, ty = 0.f, tz = 0.f, tw = 0.f;
        #pragma unroll
        for (int s = 0; s < 8; s++) {
            int b = (s * 64 + f4) * 4;
            tx += red[b + 0]; ty += red[b + 1]; tz += red[b + 2]; tw += red[b + 3];
        }
        float4 o;
        o.x = tx * inv; o.y = ty * inv; o.z = tz * inv; o.w = tw * inv;
        ((float4*)emb_out)[(long)k * 64 + f4] = o;
    }
    __syncthreads();

    // coords reduction across all 512 threads
    red[threadIdx.x]        = cx;
    red[512  + threadIdx.x] = cy;
    red[1024 + threadIdx.x] = cz;
    __syncthreads();
    for (int s = 256; s > 0; s >>= 1) {
        if (threadIdx.x < s) {
            red[threadIdx.x]        += red[threadIdx.x + s];
            red[512  + threadIdx.x] += red[512  + threadIdx.x + s];
            red[1024 + threadIdx.x] += red[1024 + threadIdx.x + s];
        }
        __syncthreads();
    }
    if (threadIdx.x == 0) {
        cent_out[k * 3 + 0] = red[0]    * inv;
        cent_out[k * 3 + 1] = red[512]  * inv;
        cent_out[k * 3 + 2] = red[1024] * inv;
    }
}

// ---------- Phase 5: MLP. One block (64 threads) per instance. ----------
__global__ __launch_bounds__(64) void mlp_kernel(const float* __restrict__ emb,
                                                 const float* __restrict__ W1,
                                                 const float* __restrict__ W2,
                                                 const float* __restrict__ W3,
                                                 const float* __restrict__ b3,
                                                 float* __restrict__ mlp_out) {
    int k = blockIdx.x;
    int j = threadIdx.x;   // 0..63
    __shared__ float e[DFEAT];
    __shared__ float h1[64];
    __shared__ float h2[64];

    float4 ev = ((const float4*)emb)[(long)k * 64 + j];
    e[j * 4 + 0] = ev.x; e[j * 4 + 1] = ev.y; e[j * 4 + 2] = ev.z; e[j * 4 + 3] = ev.w;
    __syncthreads();

    float acc = 0.f;
    #pragma unroll 8
    for (int d = 0; d < DFEAT; d++) acc += e[d] * W1[d * 64 + j];
    h1[j] = fmaxf(acc, 0.f);
    __syncthreads();

    acc = 0.f;
    #pragma unroll 8
    for (int d = 0; d < 64; d++) acc += h1[d] * W2[d * 64 + j];
    h2[j] = fmaxf(acc, 0.f);
    __syncthreads();

    if (j < OUTC) {
        float o = b3[j];
        #pragma unroll 8
        for (int d = 0; d < 64; d++) o += h2[d] * W3[d * OUTC + j];
        mlp_out[k * OUTC + j] = o;
    }
}

extern "C" void kernel_launch(void* const* d_in, const int* in_sizes, int n_in,
                              void* d_out, int out_size, void* d_ws, size_t ws_size,
                              hipStream_t stream) {
    const float* features = (const float*)d_in[0];
    const float* coords   = (const float*)d_in[1];
    const int*   ids      = (const int*)d_in[2];
    // d_in[3] = num_instances (K=512, hardcoded)
    const float* W1 = (const float*)d_in[4];
    const float* W2 = (const float*)d_in[5];
    const float* W3 = (const float*)d_in[6];
    const float* b3 = (const float*)d_in[7];

    int n = in_sizes[2];   // number of points

    float* out      = (float*)d_out;
    float* emb_out  = out;                          // [512, 256]
    float* cent_out = out + (long)KINST * DFEAT;    // [512, 3]
    float* mlp_out  = cent_out + (long)KINST * 3;   // [512, 32]

    // workspace layout (poisoned 0xAA each call -> zero what we accumulate into)
    char* ws = (char*)d_ws;
    int* counts  = (int*)(ws + 0);       // 512*4 = 2048
    int* cursor  = (int*)(ws + 2048);    // 512*4 = 2048
    int* offsets = (int*)(ws + 4096);    // 512*4 = 2048
    int* bucket  = (int*)(ws + 6144);    // n * 4

    hipMemsetAsync(d_ws, 0, 4096, stream);   // zero counts + cursor

    int blocksHS = (n + CHUNK - 1) / CHUNK;  // 123 for N=500k
    hist_kernel<<<blocksHS, 256, 0, stream>>>(ids, counts, n);
    scan_kernel<<<1, KINST, 0, stream>>>(counts, offsets);
    scatter2_kernel<<<blocksHS, 256, 0, stream>>>(ids, offsets, cursor, bucket, n);
    gather_kernel<<<KINST, 512, 0, stream>>>((const float4*)features, coords, bucket,
                                             offsets, counts, emb_out, cent_out);
    mlp_kernel<<<KINST, 64, 0, stream>>>(emb_out, W1, W2, W3, b3, mlp_out);
}